// Round 3
// baseline (779.669 us; speedup 1.0000x reference)
//
#include <hip/hip_runtime.h>
#include <hip/hip_bf16.h>

#define F 128
#define EPT 4              // edges per thread in edge_dot
#define EPB (256 * EPT)    // edges per block

typedef unsigned int uint;
typedef unsigned short ushort;
typedef __attribute__((ext_vector_type(8))) short short8;   // 8 bf16
typedef __attribute__((ext_vector_type(4))) float f32x4;

__device__ inline ushort f2bf(float f) {
    uint u = __float_as_uint(f);
    u += 0x7FFF + ((u >> 16) & 1);   // round-to-nearest-even
    return (ushort)(u >> 16);
}
__device__ inline float2 bf2f(uint u) {
    return make_float2(__uint_as_float(u << 16), __uint_as_float(u & 0xFFFF0000u));
}
__device__ inline void acc8(float* a, uint4 v) {
    float2 f;
    f = bf2f(v.x); a[0] += f.x; a[1] += f.y;
    f = bf2f(v.y); a[2] += f.x; a[3] += f.y;
    f = bf2f(v.z); a[4] += f.x; a[5] += f.y;
    f = bf2f(v.w); a[6] += f.x; a[7] += f.y;
}
__device__ inline void unp8(float* a, uint4 v) {
    float2 f;
    f = bf2f(v.x); a[0] = f.x; a[1] = f.y;
    f = bf2f(v.y); a[2] = f.x; a[3] = f.y;
    f = bf2f(v.z); a[4] = f.x; a[5] = f.y;
    f = bf2f(v.w); a[6] = f.x; a[7] = f.y;
}
// dot of two packed-bf16 uint4 (8 bf16 pairs = 8 f32 products)
__device__ inline float dpair(uint4 a, uint4 b) {
    float2 fa, fb; float s = 0.f;
    fa = bf2f(a.x); fb = bf2f(b.x); s += fa.x * fb.x + fa.y * fb.y;
    fa = bf2f(a.y); fb = bf2f(b.y); s += fa.x * fb.x + fa.y * fb.y;
    fa = bf2f(a.z); fb = bf2f(b.z); s += fa.x * fb.x + fa.y * fb.y;
    fa = bf2f(a.w); fb = bf2f(b.w); s += fa.x * fb.x + fa.y * fb.y;
    return s;
}

// ---------------- CSR build ----------------
__global__ __launch_bounds__(256) void rank_kernel(const int* __restrict__ dst,
                                                   int* __restrict__ cnt,
                                                   ushort* __restrict__ rel, int E) {
    int e = blockIdx.x * 256 + threadIdx.x;
    if (e < E) rel[e] = (ushort)atomicAdd(&cnt[dst[e]], 1);
}

__global__ __launch_bounds__(256) void scan_block(const int* __restrict__ cnt,
                                                  int* __restrict__ off,
                                                  int* __restrict__ bsum, int N) {
    __shared__ int t[256];
    int i = blockIdx.x * 256 + threadIdx.x;
    int v = (i < N) ? cnt[i] : 0;
    t[threadIdx.x] = v;
    __syncthreads();
    for (int o = 1; o < 256; o <<= 1) {
        int x = (threadIdx.x >= o) ? t[threadIdx.x - o] : 0;
        __syncthreads();
        t[threadIdx.x] += x;
        __syncthreads();
    }
    if (i < N) off[i] = t[threadIdx.x] - v;
    if (threadIdx.x == 255) bsum[blockIdx.x] = t[255];
}

__global__ __launch_bounds__(512) void scan_sums(int* __restrict__ bsum, int nb) {
    __shared__ int t[512];
    int v = (threadIdx.x < nb) ? bsum[threadIdx.x] : 0;
    t[threadIdx.x] = v;
    __syncthreads();
    for (int o = 1; o < 512; o <<= 1) {
        int x = (threadIdx.x >= o) ? t[threadIdx.x - o] : 0;
        __syncthreads();
        t[threadIdx.x] += x;
        __syncthreads();
    }
    if (threadIdx.x < nb) bsum[threadIdx.x] = t[threadIdx.x] - v;
}

__global__ __launch_bounds__(256) void scan_add_rdeg(int* __restrict__ off,
                                                     const int* __restrict__ bsum,
                                                     const int* __restrict__ cnt,
                                                     float* __restrict__ rdeg, int N) {
    int i = blockIdx.x * 256 + threadIdx.x;
    if (i >= N) return;
    off[i] += bsum[blockIdx.x];
    rdeg[i] = 1.0f / fmaxf((float)cnt[i], 1.0f);
}

__global__ __launch_bounds__(256) void fill_kernel(const int* __restrict__ src,
                                                   const int* __restrict__ dst,
                                                   const int* __restrict__ off,
                                                   const ushort* __restrict__ rel,
                                                   int* __restrict__ srcS, int E) {
    int e = blockIdx.x * 256 + threadIdx.x;
    if (e >= E) return;
    srcS[off[dst[e]] + (int)rel[e]] = src[e];
}

// ---------------- fused prep: cast x -> bf16 CHUNK-MAJOR, plus weights FRAG-MAJOR ----
// x chunk-major: [chunk=8][N][8 uints]; chunk c holds features [16c,16c+16).
// Weights fragment-major: ushort idx = (((mat*4+kk)*8+t)*64 + lane)*8 + j,
// content = bf16(W[mat][k*128 + n]) with n = 16t + (lane&15), k = 32kk + 8*(lane>>4) + j.
// -> in sage, every B-fragment load is 64 consecutive lanes x 16B = coalesced 1KB.
__global__ __launch_bounds__(256) void prep_kernel(const float* __restrict__ x,
                                                   const float* __restrict__ W0,
                                                   const float* __restrict__ W1,
                                                   const float* __restrict__ W2,
                                                   const float* __restrict__ W3,
                                                   uint* __restrict__ xb,
                                                   ushort* __restrict__ Wt, int NF4, int N) {
    int i = blockIdx.x * 256 + threadIdx.x;
    if (i < NF4) {
        float4 v = ((const float4*)x)[i];
        uint ua = (uint)f2bf(v.x) | ((uint)f2bf(v.y) << 16);
        uint ub = (uint)f2bf(v.z) | ((uint)f2bf(v.w) << 16);
        int r = i >> 5;          // node row (32 float4 per row)
        int g = i & 31;          // uint2 index within row; uint index = 2g
        int c = g >> 2;          // chunk = (2g)>>3
        int o = (g & 3) * 2;     // offset = (2g)&7
        uint* dstp = xb + (size_t)c * (size_t)N * 8 + (size_t)r * 8 + o;
        *(uint2*)dstp = make_uint2(ua, ub);
    } else {
        int idx = i - NF4;
        if (idx >= 4 * 16384) return;
        int j    = idx & 7;
        int lane = (idx >> 3) & 63;
        int t    = (idx >> 9) & 7;
        int kk   = (idx >> 12) & 3;
        int mat  = idx >> 14;
        int n = 16 * t + (lane & 15);
        int k = 32 * kk + 8 * (lane >> 4) + j;
        const float* W = (mat == 0) ? W0 : (mat == 1) ? W1 : (mat == 2) ? W2 : W3;
        Wt[idx] = f2bf(W[k * 128 + n]);
    }
}

// ---------------- aggregate: XCD-sharded, 2 lanes x 16B per edge (unchanged r2) ----------
__global__ __launch_bounds__(256) void agg_gather_cm(const uint* __restrict__ hb,  // chunk-major
                                                     const int* __restrict__ off,
                                                     const int* __restrict__ srcS,
                                                     const float* __restrict__ rdeg,
                                                     uint* __restrict__ msgb,      // chunk-major
                                                     int N, int E) {
    int chunk = blockIdx.x & 7;
    int ngrp = blockIdx.x >> 3;
    int lane = threadIdx.x & 63;
    int t = lane & 7;
    int g = lane >> 3;
    int slot = t >> 1;
    int half = t & 1;
    int node = ngrp * 32 + (threadIdx.x >> 6) * 8 + g;
    if (node >= N) return;
    const uint* hc = hb + (size_t)chunk * (size_t)N * 8;
    int p = off[node];
    int pe = (node == N - 1) ? E : off[node + 1];
    float acc[8];
#pragma unroll
    for (int j = 0; j < 8; j++) acc[j] = 0.f;
    if (p < pe) {
        int deg = pe - p;
        int last = pe - 1;
        for (; p < pe; p += 8) {
            int ia = min(p + slot, last);
            int ib = min(p + 4 + slot, last);
            int sa = srcS[ia], sb = srcS[ib];
            uint4 va = *(const uint4*)(hc + (size_t)sa * 8 + half * 4);
            uint4 vb = *(const uint4*)(hc + (size_t)sb * 8 + half * 4);
            acc8(acc, va);
            acc8(acc, vb);
        }
        int d = (8 - (deg & 7)) & 7;   // total duplicate adds of row[last] across the group
        if (d && slot == 0) {          // subtract once per half (acc is reduced across slots)
            uint4 vl = *(const uint4*)(hc + (size_t)srcS[last] * 8 + half * 4);
            float tmp[8];
            unp8(tmp, vl);
            float fd = (float)d;
#pragma unroll
            for (int j = 0; j < 8; j++) acc[j] -= fd * tmp[j];
        }
    }
#pragma unroll
    for (int j = 0; j < 8; j++) {
        acc[j] += __shfl_xor(acc[j], 2);
        acc[j] += __shfl_xor(acc[j], 4);
    }
    if (slot == 0) {
        float rd = rdeg[node];
        uint4 w;
        w.x = (uint)f2bf(acc[0] * rd) | ((uint)f2bf(acc[1] * rd) << 16);
        w.y = (uint)f2bf(acc[2] * rd) | ((uint)f2bf(acc[3] * rd) << 16);
        w.z = (uint)f2bf(acc[4] * rd) | ((uint)f2bf(acc[5] * rd) << 16);
        w.w = (uint)f2bf(acc[6] * rd) | ((uint)f2bf(acc[7] * rd) << 16);
        *(uint4*)(msgb + (size_t)chunk * (size_t)N * 8 + (size_t)node * 8 + half * 4) = w;
    }
}

// ---------------- SAGE layer via MFMA (chunk-major in AND out, frag-major weights) -------
__global__ __launch_bounds__(256) void sage_mfma(const uint* __restrict__ hb,
                                                 const uint* __restrict__ mb,
                                                 const uint* __restrict__ Wt,  // frag-major
                                                 const float* __restrict__ bias,
                                                 ushort* __restrict__ outb, int N) {
    int wave = threadIdx.x >> 6, lane = threadIdx.x & 63;
    int m = lane & 15, q = lane >> 4;
    int r0 = blockIdx.x * 64 + wave * 16;
    int arow = r0 + m;
    if (arow >= N) arow = N - 1;

    f32x4 acc[8];
#pragma unroll
    for (int t = 0; t < 8; t++) acc[t] = (f32x4){0.f, 0.f, 0.f, 0.f};

    size_t N8 = (size_t)N * 8;
#pragma unroll
    for (int sel = 0; sel < 2; sel++) {
        const uint* arowp = (sel ? mb : hb) + (size_t)arow * 8 + (q & 1) * 4;
        const uint* wsel = Wt + sel * 8192;
#pragma unroll
        for (int kk = 0; kk < 4; kk++) {
            short8 a = *(const short8*)(arowp + (size_t)(kk * 2 + (q >> 1)) * N8);
#pragma unroll
            for (int t = 0; t < 8; t++) {
                // coalesced: all 64 lanes read consecutive 16B -> one 1KB line burst
                short8 b = *(const short8*)(wsel + (size_t)((kk * 8 + t) * 64 + lane) * 4);
                acc[t] = __builtin_amdgcn_mfma_f32_16x16x32_bf16(a, b, acc[t], 0, 0, 0);
            }
        }
    }

    // chunk-major output: feature group t (16 feats) = chunk t, element m
#pragma unroll
    for (int t = 0; t < 8; t++) {
        float bs = bias[16 * t + m];
#pragma unroll
        for (int r = 0; r < 4; r++) {
            int orow = r0 + q * 4 + r;
            if (orow < N)
                outb[(size_t)t * (size_t)N * 16 + (size_t)orow * 16 + m] = f2bf(acc[t][r] + bs);
        }
    }
}

// ---------------- edge scores: chunk-outer register-accumulated dots ----------------
// Each thread owns EPT edges (idx+acc in regs) and loops over the 8 feature chunks.
// Blocks XCD-pinned (blockIdx&7); each XCD starts at its own chunk -> per-XCD L2 holds
// exactly one 3.2MB chunk region at a time. No pbuf, sc dense in ORIGINAL edge order.
__global__ __launch_bounds__(256) void edge_dot(const uint* __restrict__ hb,  // chunk-major h2
                                                const int* __restrict__ src,
                                                const int* __restrict__ dst,
                                                float* __restrict__ sc,
                                                float2* __restrict__ pmm, int N, int E) {
    int xcd = blockIdx.x & 7;
    int ebase = blockIdx.x * EPB + threadIdx.x;
    int si[EPT], di[EPT];
    float acc[EPT];
#pragma unroll
    for (int j = 0; j < EPT; j++) {
        int e = ebase + j * 256;
        int ec = (e < E) ? e : E - 1;
        si[j] = src[ec];
        di[j] = dst[ec];
        acc[j] = 0.f;
    }
    size_t N8 = (size_t)N * 8;
    for (int cc = 0; cc < 8; cc++) {
        int c = (cc + xcd) & 7;
        const uint* hc = hb + (size_t)c * N8;
#pragma unroll
        for (int j = 0; j < EPT; j++) {
            const uint* sp = hc + (size_t)si[j] * 8;
            const uint* dp = hc + (size_t)di[j] * 8;
            uint4 a0 = *(const uint4*)sp;
            uint4 a1 = *(const uint4*)(sp + 4);
            uint4 b0 = *(const uint4*)dp;
            uint4 b1 = *(const uint4*)(dp + 4);
            acc[j] += dpair(a0, b0) + dpair(a1, b1);
        }
    }
    float lmin = INFINITY, lmax = -INFINITY;
#pragma unroll
    for (int j = 0; j < EPT; j++) {
        int e = ebase + j * 256;
        if (e < E) {
            sc[e] = acc[j];
            lmin = fminf(lmin, acc[j]);
            lmax = fmaxf(lmax, acc[j]);
        }
    }
#pragma unroll
    for (int o = 1; o <= 32; o <<= 1) {
        lmin = fminf(lmin, __shfl_xor(lmin, o));
        lmax = fmaxf(lmax, __shfl_xor(lmax, o));
    }
    __shared__ float smin[4], smax[4];
    int lane = threadIdx.x & 63, wv = threadIdx.x >> 6;
    if (lane == 0) { smin[wv] = lmin; smax[wv] = lmax; }
    __syncthreads();
    if (threadIdx.x == 0) {
        float mA = fminf(fminf(smin[0], smin[1]), fminf(smin[2], smin[3]));
        float MA = fmaxf(fmaxf(smax[0], smax[1]), fmaxf(smax[2], smax[3]));
        pmm[blockIdx.x] = make_float2(mA, MA);
    }
}

__global__ __launch_bounds__(1024) void minmax_final(const float2* __restrict__ pmm,
                                                     float* __restrict__ mmf, int nb) {
    float vmin = INFINITY, vmax = -INFINITY;
    for (int i = threadIdx.x; i < nb; i += 1024) {
        float2 v = pmm[i];
        vmin = fminf(vmin, v.x);
        vmax = fmaxf(vmax, v.y);
    }
#pragma unroll
    for (int o = 1; o <= 32; o <<= 1) {
        vmin = fminf(vmin, __shfl_xor(vmin, o));
        vmax = fmaxf(vmax, __shfl_xor(vmax, o));
    }
    __shared__ float smin[16], smax[16];
    int lane = threadIdx.x & 63, wv = threadIdx.x >> 6;
    if (lane == 0) { smin[wv] = vmin; smax[wv] = vmax; }
    __syncthreads();
    if (threadIdx.x == 0) {
        float m = smin[0], M = smax[0];
        for (int w = 1; w < 16; w++) { m = fminf(m, smin[w]); M = fmaxf(M, smax[w]); }
        mmf[0] = m;
        mmf[1] = M;
    }
}

// dense float4 normalize: out[e] = (sc[e] - mn) * inv
__global__ __launch_bounds__(256) void norm4_kernel(const float* __restrict__ sc,
                                                    float* __restrict__ out,
                                                    const float* __restrict__ mmf, int E4) {
    int i = blockIdx.x * 256 + threadIdx.x;
    if (i >= E4) return;
    float mn = mmf[0];
    float inv = 1.0f / (mmf[1] - mn);
    float4 v = ((const float4*)sc)[i];
    v.x = (v.x - mn) * inv;
    v.y = (v.y - mn) * inv;
    v.z = (v.z - mn) * inv;
    v.w = (v.w - mn) * inv;
    ((float4*)out)[i] = v;
}

extern "C" void kernel_launch(void* const* d_in, const int* in_sizes, int n_in,
                              void* d_out, int out_size, void* d_ws, size_t ws_size,
                              hipStream_t stream) {
    const float* x   = (const float*)d_in[0];
    const int*   src = (const int*)d_in[1];
    const int*   dst = (const int*)d_in[2];
    const float* Ws1 = (const float*)d_in[3];
    const float* Wn1 = (const float*)d_in[4];
    const float* b1  = (const float*)d_in[5];
    const float* Ws2 = (const float*)d_in[6];
    const float* Wn2 = (const float*)d_in[7];
    const float* b2  = (const float*)d_in[8];

    int N = in_sizes[0] / F;   // 100000
    int E = in_sizes[1];       // 1600000
    float* out = (float*)d_out;

    int nbN = (N + 255) / 256;
    int nbE = (E + 255) / 256;
    int NF4 = N * F / 4;

    // workspace layout (4-byte elements)
    int* off  = (int*)d_ws;                  // N
    int* cnt  = off + N;                     // N
    int* srcS = cnt + N;                     // E
    ushort* rel = (ushort*)(srcS + E);       // E ushorts = E/2 words
    float* sc = (float*)((int*)rel + E / 2); // E
    int* bsum = (int*)(sc + E);              // 1024
    float* rdeg = (float*)(bsum + 1024);     // N
    float* mmf = (float*)(rdeg + N);         // 2 (+2 pad)
    float2* pmm = (float2*)(mmf + 4);        // up to 25600 float2
    uint* Wtb = (uint*)(pmm + 25600);        // 32768 uints (frag-major)
    size_t elemOff = 3 * (size_t)N + 2 * (size_t)E + (size_t)E / 2 + 1024 + 4 + 51200 + 32768;
    elemOff = (elemOff + 3) & ~(size_t)3;    // 16B align
    uint* xb   = (uint*)d_ws + elemOff;      // N*64  (chunk-major)
    uint* msgb = xb + (size_t)N * 64;        // N*64  (chunk-major)
    uint* h1b  = msgb + (size_t)N * 64;      // N*64  (chunk-major)
    uint* h2b  = h1b + (size_t)N * 64;       // N*64  (chunk-major)

    // init
    hipMemsetAsync(cnt, 0, (size_t)N * sizeof(int), stream);

    // CSR build (by dst): one atomic pass + scan + atomic-free fill
    rank_kernel<<<nbE, 256, 0, stream>>>(dst, cnt, rel, E);
    scan_block<<<nbN, 256, 0, stream>>>(cnt, off, bsum, N);
    scan_sums<<<1, 512, 0, stream>>>(bsum, nbN);
    scan_add_rdeg<<<nbN, 256, 0, stream>>>(off, bsum, cnt, rdeg, N);
    fill_kernel<<<nbE, 256, 0, stream>>>(src, dst, off, rel, srcS, E);

    // fused weights (frag-major) + input cast (chunk-major x)
    prep_kernel<<<(NF4 + 4 * 16384 + 255) / 256, 256, 0, stream>>>(
        x, Ws1, Wn1, Ws2, Wn2, xb, (ushort*)Wtb, NF4, N);

    int nbAgg = 8 * ((N + 31) / 32);   // chunk = blockIdx&7 -> XCD-pinned

    // layer 1
    agg_gather_cm<<<nbAgg, 256, 0, stream>>>(xb, off, srcS, rdeg, msgb, N, E);
    sage_mfma<<<(N + 63) / 64, 256, 0, stream>>>(xb, msgb, Wtb, b1, (ushort*)h1b, N);

    // layer 2 (chunk-major output feeds edge_dot)
    agg_gather_cm<<<nbAgg, 256, 0, stream>>>(h1b, off, srcS, rdeg, msgb, N, E);
    sage_mfma<<<(N + 63) / 64, 256, 0, stream>>>(h1b, msgb, Wtb + 16384, b2, (ushort*)h2b, N);

    // edge scores: register-accumulated chunk-outer dots (dense sc) -> minmax -> normalize
    int nbDot = (E + EPB - 1) / EPB;
    edge_dot<<<nbDot, 256, 0, stream>>>(h2b, src, dst, sc, pmm, N, E);
    minmax_final<<<1, 1024, 0, stream>>>(pmm, mmf, nbDot);
    norm4_kernel<<<(E / 4 + 255) / 256, 256, 0, stream>>>(sc, out, mmf, E / 4);
}

// Round 4
// 548.967 us; speedup vs baseline: 1.4202x; 1.4202x over previous
//
#include <hip/hip_runtime.h>
#include <hip/hip_bf16.h>

#define F 128

typedef unsigned int uint;
typedef unsigned short ushort;
typedef __attribute__((ext_vector_type(8))) short short8;   // 8 bf16
typedef __attribute__((ext_vector_type(4))) float f32x4;

__device__ inline ushort f2bf(float f) {
    uint u = __float_as_uint(f);
    u += 0x7FFF + ((u >> 16) & 1);   // round-to-nearest-even
    return (ushort)(u >> 16);
}
__device__ inline float2 bf2f(uint u) {
    return make_float2(__uint_as_float(u << 16), __uint_as_float(u & 0xFFFF0000u));
}

// ---------------- CSR build ----------------
// pass 1: histogram + per-edge relative rank within its dst bucket (ONE atomic pass)
__global__ __launch_bounds__(256) void rank_kernel(const int* __restrict__ dst,
                                                   int* __restrict__ cnt,
                                                   ushort* __restrict__ rel, int E) {
    int e = blockIdx.x * 256 + threadIdx.x;
    if (e < E) rel[e] = (ushort)atomicAdd(&cnt[dst[e]], 1);
}

__global__ __launch_bounds__(256) void scan_block(const int* __restrict__ cnt,
                                                  int* __restrict__ off,
                                                  int* __restrict__ bsum, int N) {
    __shared__ int t[256];
    int i = blockIdx.x * 256 + threadIdx.x;
    int v = (i < N) ? cnt[i] : 0;
    t[threadIdx.x] = v;
    __syncthreads();
    for (int o = 1; o < 256; o <<= 1) {
        int x = (threadIdx.x >= o) ? t[threadIdx.x - o] : 0;
        __syncthreads();
        t[threadIdx.x] += x;
        __syncthreads();
    }
    if (i < N) off[i] = t[threadIdx.x] - v;
    if (threadIdx.x == 255) bsum[blockIdx.x] = t[255];
}

__global__ __launch_bounds__(512) void scan_sums(int* __restrict__ bsum, int nb) {
    __shared__ int t[512];
    int v = (threadIdx.x < nb) ? bsum[threadIdx.x] : 0;
    t[threadIdx.x] = v;
    __syncthreads();
    for (int o = 1; o < 512; o <<= 1) {
        int x = (threadIdx.x >= o) ? t[threadIdx.x - o] : 0;
        __syncthreads();
        t[threadIdx.x] += x;
        __syncthreads();
    }
    if (threadIdx.x < nb) bsum[threadIdx.x] = t[threadIdx.x] - v;
}

// finalize offsets + rdeg
__global__ __launch_bounds__(256) void scan_add_rdeg(int* __restrict__ off,
                                                     const int* __restrict__ bsum,
                                                     const int* __restrict__ cnt,
                                                     float* __restrict__ rdeg, int N) {
    int i = blockIdx.x * 256 + threadIdx.x;
    if (i >= N) return;
    off[i] += bsum[blockIdx.x];
    rdeg[i] = 1.0f / fmaxf((float)cnt[i], 1.0f);
}

// pass 2: atomic-free fill (no rank store; norm recomputes it)
__global__ __launch_bounds__(256) void fill_kernel(const int* __restrict__ src,
                                                   const int* __restrict__ dst,
                                                   const int* __restrict__ off,
                                                   const ushort* __restrict__ rel,
                                                   int* __restrict__ srcS, int E) {
    int e = blockIdx.x * 256 + threadIdx.x;
    if (e >= E) return;
    srcS[off[dst[e]] + (int)rel[e]] = src[e];
}

// ---------------- fused prep: cast x -> bf16 rows, plus weight cast + FRAG-MAJOR swizzle --
// x: row-major bf16-packed [N][64 uints].
// Weights fragment-major: ushort idx = (((mat*4+kk)*8+t)*64 + lane)*8 + j, containing
// bf16(W[mat][k*128+n]) with n = 16t + (lane&15), k = 32kk + 8*(lane>>4) + j.
// -> in sage_mfma every B-fragment load is 64 lanes x consecutive 16B = one 1KB burst
//    (was: 16B/lane at stride 256B = 64 scattered segments per instruction).
__global__ __launch_bounds__(256) void prep_kernel(const float* __restrict__ x,
                                                   const float* __restrict__ W0,
                                                   const float* __restrict__ W1,
                                                   const float* __restrict__ W2,
                                                   const float* __restrict__ W3,
                                                   uint* __restrict__ xb,
                                                   ushort* __restrict__ Wt, int NF4) {
    int i = blockIdx.x * 256 + threadIdx.x;
    if (i < NF4) {
        float4 v = ((const float4*)x)[i];
        uint ua = (uint)f2bf(v.x) | ((uint)f2bf(v.y) << 16);
        uint ub = (uint)f2bf(v.z) | ((uint)f2bf(v.w) << 16);
        ((uint2*)xb)[i] = make_uint2(ua, ub);
    } else {
        int idx = i - NF4;
        if (idx >= 4 * 16384) return;
        int j    = idx & 7;
        int lane = (idx >> 3) & 63;
        int t    = (idx >> 9) & 7;
        int kk   = (idx >> 12) & 3;
        int mat  = idx >> 14;
        int n = 16 * t + (lane & 15);
        int k = 32 * kk + 8 * (lane >> 4) + j;
        const float* W = (mat == 0) ? W0 : (mat == 1) ? W1 : (mat == 2) ? W2 : W3;
        Wt[idx] = f2bf(W[k * 128 + n]);
    }
}

// ---------------- aggregate (gather, rounded-up unroll 8, no serial tail) ----------------
// wave per node, lane = feature pair; indices wave-uniform (scalar loads).
// Loop rounds deg up to a multiple of 8 with idx clamped to last; the d duplicate
// adds of row[last] are subtracted afterwards (one extra coalesced load + 2 FMA).
__global__ __launch_bounds__(256) void agg_gather(const uint* __restrict__ hb,
                                                  const int* __restrict__ off,
                                                  const int* __restrict__ srcS,
                                                  const float* __restrict__ rdeg,
                                                  uint* __restrict__ msgb, int N, int E) {
    int node = blockIdx.x * 4 + (threadIdx.x >> 6);
    int lane = threadIdx.x & 63;
    if (node >= N) return;
    int p = off[node];
    int pe = (node == N - 1) ? E : off[node + 1];
    float2 acc = make_float2(0.f, 0.f);
    if (p < pe) {
        int deg = pe - p;
        int last = pe - 1;
        for (; p < pe; p += 8) {
            int i0 = min(p + 0, last), i1 = min(p + 1, last);
            int i2 = min(p + 2, last), i3 = min(p + 3, last);
            int i4 = min(p + 4, last), i5 = min(p + 5, last);
            int i6 = min(p + 6, last), i7 = min(p + 7, last);
            int s0 = srcS[i0], s1 = srcS[i1], s2 = srcS[i2], s3 = srcS[i3];
            int s4 = srcS[i4], s5 = srcS[i5], s6 = srcS[i6], s7 = srcS[i7];
            float2 f0 = bf2f(hb[(size_t)s0 * 64 + lane]);
            float2 f1 = bf2f(hb[(size_t)s1 * 64 + lane]);
            float2 f2 = bf2f(hb[(size_t)s2 * 64 + lane]);
            float2 f3 = bf2f(hb[(size_t)s3 * 64 + lane]);
            float2 f4 = bf2f(hb[(size_t)s4 * 64 + lane]);
            float2 f5 = bf2f(hb[(size_t)s5 * 64 + lane]);
            float2 f6 = bf2f(hb[(size_t)s6 * 64 + lane]);
            float2 f7 = bf2f(hb[(size_t)s7 * 64 + lane]);
            acc.x += ((f0.x + f1.x) + (f2.x + f3.x)) + ((f4.x + f5.x) + (f6.x + f7.x));
            acc.y += ((f0.y + f1.y) + (f2.y + f3.y)) + ((f4.y + f5.y) + (f6.y + f7.y));
        }
        int d = (8 - (deg & 7)) & 7;          // duplicate count of row[last]
        if (d) {
            float2 fl = bf2f(hb[(size_t)srcS[last] * 64 + lane]);
            float fd = (float)d;
            acc.x -= fd * fl.x;
            acc.y -= fd * fl.y;
        }
    }
    float rd = rdeg[node];
    msgb[(size_t)node * 64 + lane] = (uint)f2bf(acc.x * rd) | ((uint)f2bf(acc.y * rd) << 16);
}

// ---------------- SAGE layer via MFMA (frag-major weights) ----------------
__global__ __launch_bounds__(256) void sage_mfma(const uint* __restrict__ hb,
                                                 const uint* __restrict__ mb,
                                                 const uint* __restrict__ Wt,  // frag-major
                                                 const float* __restrict__ bias,
                                                 ushort* __restrict__ outb, int N) {
    int wave = threadIdx.x >> 6, lane = threadIdx.x & 63;
    int m = lane & 15, q = lane >> 4;
    int r0 = blockIdx.x * 64 + wave * 16;
    int arow = r0 + m;
    if (arow >= N) arow = N - 1;

    f32x4 acc[8];
#pragma unroll
    for (int t = 0; t < 8; t++) acc[t] = (f32x4){0.f, 0.f, 0.f, 0.f};

    const uint* hrow = hb + (size_t)arow * 64;
    const uint* mrow = mb + (size_t)arow * 64;
#pragma unroll
    for (int sel = 0; sel < 2; sel++) {
        const uint* arowp = sel ? mrow : hrow;
        const uint* wsel = Wt + sel * 8192;
#pragma unroll
        for (int kk = 0; kk < 4; kk++) {
            int ko = kk * 16 + q * 4;
            short8 a = *(const short8*)(arowp + ko);
#pragma unroll
            for (int t = 0; t < 8; t++) {
                // frag-major: 64 lanes read consecutive 16B -> one contiguous 1KB access
                short8 b = *(const short8*)(wsel + (size_t)((kk * 8 + t) * 64 + lane) * 4);
                acc[t] = __builtin_amdgcn_mfma_f32_16x16x32_bf16(a, b, acc[t], 0, 0, 0);
            }
        }
    }

#pragma unroll
    for (int t = 0; t < 8; t++) {
        float bs = bias[16 * t + m];
#pragma unroll
        for (int r = 0; r < 4; r++) {
            int orow = r0 + q * 4 + r;
            if (orow < N) outb[(size_t)orow * 128 + 16 * t + m] = f2bf(acc[t][r] + bs);
        }
    }
}

// ---------------- edge score via MFMA matrix-vector: 16 edges per batch ----------------
__global__ __launch_bounds__(256) void edge_score_mfma(const uint* __restrict__ hb,
                                                       const int* __restrict__ off,
                                                       const int* __restrict__ srcS,
                                                       float* __restrict__ sc,
                                                       float2* __restrict__ pmm, int N, int E) {
    int node = blockIdx.x * 4 + (threadIdx.x >> 6);
    int lane = threadIdx.x & 63;
    int m = lane & 15, q = lane >> 4;
    float lmin = INFINITY, lmax = -INFINITY;

    if (node < N) {
        int p = off[node];
        int pe = (node == N - 1) ? E : off[node + 1];
        if (p < pe) {
            const uint* nrow = hb + (size_t)node * 64;
            short8 bfr[4];
#pragma unroll
            for (int kk = 0; kk < 4; kk++)
                bfr[kk] = *(const short8*)(nrow + kk * 16 + q * 4);   // B[k][n]=h_node[k] ∀n

            for (; p < pe; p += 16) {
                int idx = p + m;
                if (idx >= pe) idx = pe - 1;                  // clamp: dup rows, stores masked
                const uint* arow = hb + (size_t)srcS[idx] * 64;
                f32x4 acc = (f32x4){0.f, 0.f, 0.f, 0.f};
#pragma unroll
                for (int kk = 0; kk < 4; kk++) {
                    short8 a = *(const short8*)(arow + kk * 16 + q * 4);
                    acc = __builtin_amdgcn_mfma_f32_16x16x32_bf16(a, bfr[kk], acc, 0, 0, 0);
                }
                // D: col=lane&15, row=q*4+r (cols identical) -> col-0 lanes own edges q*4..q*4+3
                if (m == 0) {
                    if (p + 16 <= pe) {
                        *(float4*)(sc + p + q * 4) = make_float4(acc[0], acc[1], acc[2], acc[3]);
                        float mn = fminf(fminf(acc[0], acc[1]), fminf(acc[2], acc[3]));
                        float mx = fmaxf(fmaxf(acc[0], acc[1]), fmaxf(acc[2], acc[3]));
                        lmin = fminf(lmin, mn);
                        lmax = fmaxf(lmax, mx);
                    } else {
#pragma unroll
                        for (int r = 0; r < 4; r++) {
                            int e = p + q * 4 + r;
                            if (e < pe) {
                                sc[e] = acc[r];
                                lmin = fminf(lmin, acc[r]);
                                lmax = fmaxf(lmax, acc[r]);
                            }
                        }
                    }
                }
            }
        }
    }

#pragma unroll
    for (int o = 1; o <= 32; o <<= 1) {
        lmin = fminf(lmin, __shfl_xor(lmin, o));
        lmax = fmaxf(lmax, __shfl_xor(lmax, o));
    }
    __shared__ float smin[4], smax[4];
    int wv = threadIdx.x >> 6;
    if (lane == 0) { smin[wv] = lmin; smax[wv] = lmax; }
    __syncthreads();
    if (threadIdx.x == 0) {
        float mA = fminf(fminf(smin[0], smin[1]), fminf(smin[2], smin[3]));
        float MA = fmaxf(fmaxf(smax[0], smax[1]), fmaxf(smax[2], smax[3]));
        pmm[blockIdx.x] = make_float2(mA, MA);
    }
}

__global__ __launch_bounds__(1024) void minmax_final(const float2* __restrict__ pmm,
                                                     float* __restrict__ mmf, int nb) {
    float vmin = INFINITY, vmax = -INFINITY;
    for (int i = threadIdx.x; i < nb; i += 1024) {
        float2 v = pmm[i];
        vmin = fminf(vmin, v.x);
        vmax = fmaxf(vmax, v.y);
    }
#pragma unroll
    for (int o = 1; o <= 32; o <<= 1) {
        vmin = fminf(vmin, __shfl_xor(vmin, o));
        vmax = fmaxf(vmax, __shfl_xor(vmax, o));
    }
    __shared__ float smin[16], smax[16];
    int lane = threadIdx.x & 63, wv = threadIdx.x >> 6;
    if (lane == 0) { smin[wv] = vmin; smax[wv] = vmax; }
    __syncthreads();
    if (threadIdx.x == 0) {
        float m = smin[0], M = smax[0];
        for (int w = 1; w < 16; w++) { m = fminf(m, smin[w]); M = fmaxf(M, smax[w]); }
        mmf[0] = m;
        mmf[1] = M;
    }
}

// out[e] = (sc[off[dst[e]] + rel[e]] - mn) * inv
__global__ __launch_bounds__(256) void norm_kernel(const float* __restrict__ sc,
                                                   const int* __restrict__ dst,
                                                   const ushort* __restrict__ rel,
                                                   const int* __restrict__ off,
                                                   float* __restrict__ out,
                                                   const float* __restrict__ mmf, int E) {
    float mn = mmf[0];
    float mx = mmf[1];
    float inv = 1.0f / (mx - mn);
    int i = blockIdx.x * 256 + threadIdx.x;
    if (i < E) {
        int p = off[dst[i]] + (int)rel[i];
        out[i] = (sc[p] - mn) * inv;
    }
}

extern "C" void kernel_launch(void* const* d_in, const int* in_sizes, int n_in,
                              void* d_out, int out_size, void* d_ws, size_t ws_size,
                              hipStream_t stream) {
    const float* x   = (const float*)d_in[0];
    const int*   src = (const int*)d_in[1];
    const int*   dst = (const int*)d_in[2];
    const float* Ws1 = (const float*)d_in[3];
    const float* Wn1 = (const float*)d_in[4];
    const float* b1  = (const float*)d_in[5];
    const float* Ws2 = (const float*)d_in[6];
    const float* Wn2 = (const float*)d_in[7];
    const float* b2  = (const float*)d_in[8];

    int N = in_sizes[0] / F;   // 100000
    int E = in_sizes[1];       // 1600000
    float* out = (float*)d_out;

    int nbN = (N + 255) / 256;
    int nbE = (E + 255) / 256;
    int nbEdgeBlocks = (N + 3) / 4;       // 25000
    int NF4 = N * F / 4;

    // workspace layout (4-byte elements)
    int* off  = (int*)d_ws;                  // N
    int* cnt  = off + N;                     // N
    int* srcS = cnt + N;                     // E
    ushort* rel = (ushort*)(srcS + E);       // E ushorts = E/2 words
    float* sc = (float*)((int*)rel + E / 2); // E
    int* bsum = (int*)(sc + E);              // 1024
    float* rdeg = (float*)(bsum + 1024);     // N
    float* mmf = (float*)(rdeg + N);         // 2 (+2 pad)
    float2* pmm = (float2*)(mmf + 4);        // 25600 float2
    uint* Wtb = (uint*)(pmm + 25600);        // 32768 uints (frag-major)
    size_t elemOff = 3 * (size_t)N + 2 * (size_t)E + (size_t)E / 2 + 1024 + 4 + 51200 + 32768;
    elemOff = (elemOff + 3) & ~(size_t)3;    // 16B align
    uint* xb   = (uint*)d_ws + elemOff;      // N*64
    uint* msgb = xb + (size_t)N * 64;        // N*64
    uint* h1b  = msgb + (size_t)N * 64;      // N*64
    uint* h2b  = h1b + (size_t)N * 64;       // N*64

    // init
    hipMemsetAsync(cnt, 0, (size_t)N * sizeof(int), stream);

    // CSR build (by dst): one atomic pass + scan + atomic-free fill
    rank_kernel<<<nbE, 256, 0, stream>>>(dst, cnt, rel, E);
    scan_block<<<nbN, 256, 0, stream>>>(cnt, off, bsum, N);
    scan_sums<<<1, 512, 0, stream>>>(bsum, nbN);
    scan_add_rdeg<<<nbN, 256, 0, stream>>>(off, bsum, cnt, rdeg, N);
    fill_kernel<<<nbE, 256, 0, stream>>>(src, dst, off, rel, srcS, E);

    // fused weights (frag-major) + input cast
    prep_kernel<<<(NF4 + 4 * 16384 + 255) / 256, 256, 0, stream>>>(
        x, Ws1, Wn1, Ws2, Wn2, xb, (ushort*)Wtb, NF4);

    // layer 1
    agg_gather<<<(N + 3) / 4, 256, 0, stream>>>(xb, off, srcS, rdeg, msgb, N, E);
    sage_mfma<<<(N + 63) / 64, 256, 0, stream>>>(xb, msgb, Wtb, b1, (ushort*)h1b, N);

    // layer 2
    agg_gather<<<(N + 3) / 4, 256, 0, stream>>>(h1b, off, srcS, rdeg, msgb, N, E);
    sage_mfma<<<(N + 63) / 64, 256, 0, stream>>>(h1b, msgb, Wtb + 16384, b2, (ushort*)h2b, N);

    // edge scores via MFMA (CSR order + per-block partials) + final reduce + permute-normalize
    edge_score_mfma<<<nbEdgeBlocks, 256, 0, stream>>>(h2b, off, srcS, sc, pmm, N, E);
    minmax_final<<<1, 1024, 0, stream>>>(pmm, mmf, nbEdgeBlocks);
    norm_kernel<<<(E + 255) / 256, 256, 0, stream>>>(sc, dst, rel, off, out, mmf, E);
}